// Round 6
// baseline (165.270 us; speedup 1.0000x reference)
//
#include <hip/hip_runtime.h>
#include <math.h>

#define C_DIM 1000
#define BIG   1.0e30f   // pad: u huge -> rcp underflows -> self-masking in all sums

__device__ __forceinline__ float fexp2(float x) { return __builtin_amdgcn_exp2f(x); }
__device__ __forceinline__ float flog2(float x) { return __builtin_amdgcn_logf(x); }
__device__ __forceinline__ float frcp(float x)  { return __builtin_amdgcn_rcpf(x); }

// One wave per row; 4 generations of blocks (LDS-capped residency) give
// CU-level load/compute overlap that in-register prefetch couldn't (R5: the
// compiler sank prefetch loads to keep VGPR=52).
__global__ __launch_bounds__(256) void btll(
    const float* __restrict__ inputs, const float* __restrict__ targets,
    float* __restrict__ out, int n_rows, float inv_n,
    float C0, float E_off, float dE)
{
    // 40 KB -> max 4 blocks/CU (160/40); grid 4096 -> 4 generations.
    __shared__ float lds_cap[10240];

    const int lane = threadIdx.x & 63;
    const int wave = threadIdx.x >> 6;
    const int row  = blockIdx.x * 4 + wave;

    float loss = 0.0f;
    if (row < n_rows) {
        const float4* in4 = (const float4*)(inputs  + (size_t)row * C_DIM);
        const float4* tg4 = (const float4*)(targets + (size_t)row * C_DIM);
        const bool m3 = (lane + 192) < 250;   // only j=3 needs tail masking

        // ---- issue all 8 loads up front (coalesced 16B/lane) ----
        float4 x0 = in4[lane];
        float4 x1 = in4[lane + 64];
        float4 x2 = in4[lane + 128];
        float4 x3 = m3 ? in4[lane + 192] : make_float4(-BIG, -BIG, -BIG, -BIG);
        float4 t0 = tg4[lane];
        float4 t1 = tg4[lane + 64];
        float4 t2 = tg4[lane + 128];
        float4 t3 = m3 ? tg4[lane + 192] : make_float4(0.f, 0.f, 0.f, 0.f);

        float a[16];
        a[0]=x0.x; a[1]=x0.y; a[2]=x0.z; a[3]=x0.w;
        a[4]=x1.x; a[5]=x1.y; a[6]=x1.z; a[7]=x1.w;
        a[8]=x2.x; a[9]=x2.y; a[10]=x2.z; a[11]=x2.w;
        a[12]=x3.x; a[13]=x3.y; a[14]=x3.z; a[15]=x3.w;

        // hot-class logit (targets are raw one-hot {0,1}) + row max, jointly
        float ah = 0.0f;
        ah = fmaf(t0.x, a[0], ah);  ah = fmaf(t0.y, a[1], ah);
        ah = fmaf(t0.z, a[2], ah);  ah = fmaf(t0.w, a[3], ah);
        ah = fmaf(t1.x, a[4], ah);  ah = fmaf(t1.y, a[5], ah);
        ah = fmaf(t1.z, a[6], ah);  ah = fmaf(t1.w, a[7], ah);
        ah = fmaf(t2.x, a[8], ah);  ah = fmaf(t2.y, a[9], ah);
        ah = fmaf(t2.z, a[10], ah); ah = fmaf(t2.w, a[11], ah);
        ah = fmaf(t3.x, a[12], ah); ah = fmaf(t3.y, a[13], ah);
        ah = fmaf(t3.z, a[14], ah); ah = fmaf(t3.w, a[15], ah);

        float mu = a[0];
        #pragma unroll
        for (int k = 1; k < 16; ++k) mu = fmaxf(mu, a[k]);
        #pragma unroll
        for (int off = 32; off > 0; off >>= 1) {
            ah += __shfl_xor(ah, off, 64);
            mu  = fmaxf(mu, __shfl_xor(mu, off, 64));
        }

        float b[16];
        #pragma unroll
        for (int k = 0; k < 16; ++k) b[k] = -0.2f * (a[k] - mu);  // pad -> ~2e29
        const float hb = -0.2f * (ah - mu);

        // ---- sweep 1: s = sum (1+b)^-5  (lam = 1) ----
        float s = 0.0f;
        #pragma unroll
        for (int k = 0; k < 16; ++k) {
            float u = 1.0f + b[k];
            float u2 = u * u;
            s += frcp(u2 * u2 * u);
        }
        #pragma unroll
        for (int off = 32; off > 0; off >>= 1) s += __shfl_xor(s, off, 64);
        const float lam = fexp2(-0.2f * flog2(s));

        // ---- sweep 2: s at lam -> w0 = s^0.2 ----
        s = 0.0f;
        #pragma unroll
        for (int k = 0; k < 16; ++k) {
            float u = fmaf(lam, b[k], 1.0f);
            float u2 = u * u;
            s += frcp(u2 * u2 * u);
        }
        #pragma unroll
        for (int off = 32; off > 0; off >>= 1) s += __shfl_xor(s, off, 64);
        float w = fexp2(0.2f * flog2(s));

        // ---- sweep 3: Newton on g(w) = sum (w+b)^-5 - 1 (convex: globally safe) ----
        {
            float s5 = 0.0f, s6 = 0.0f;
            #pragma unroll
            for (int k = 0; k < 16; ++k) {
                float r  = frcp(w + b[k]);
                float r2 = r * r;
                float r4 = r2 * r2;
                float r5 = r4 * r;
                s5 += r5;
                s6 += r5 * r;
            }
            #pragma unroll
            for (int off = 32; off > 0; off >>= 1) {
                s5 += __shfl_xor(s5, off, 64);
                s6 += __shfl_xor(s6, off, 64);
            }
            w = fmaf((s5 - 1.0f) * 0.2f, frcp(s6), w);
        }

        // ---- sweep 4: merged Newton-2 + loss sums, first-order corrected ----
        {
            float S4 = 0.0f, S5 = 0.0f, S6 = 0.0f, S9 = 0.0f, S10 = 0.0f;
            #pragma unroll
            for (int k = 0; k < 16; ++k) {
                float r  = frcp(w + b[k]);
                float r2 = r * r;
                float r4 = r2 * r2;
                float r5 = r4 * r;
                S4  += r4;
                S5  += r5;
                S6  += r5 * r;
                S9  += r4 * r5;
                S10 += r5 * r5;
            }
            #pragma unroll
            for (int off = 32; off > 0; off >>= 1) {
                S4  += __shfl_xor(S4,  off, 64);
                S5  += __shfl_xor(S5,  off, 64);
                S6  += __shfl_xor(S6,  off, 64);
                S9  += __shfl_xor(S9,  off, 64);
                S10 += __shfl_xor(S10, off, 64);
            }
            const float d  = (S5 - 1.0f) * 0.2f * frcp(S6);   // Newton-2 step (~1e-7)
            const float w1 = w + d;
            const float S4c = fmaf(-4.0f * d, S5,  S4);       // S4(w1), 1st order
            const float S9c = fmaf(-9.0f * d, S10, S9);       // S9(w1), 1st order
            const float rh  = frcp(w1 + hb);
            const float rh2 = rh * rh;
            const float rh4 = rh2 * rh2;
            loss = fmaf(-E_off, S4c,
                   fmaf(-dE, rh4,
                   fmaf(1.0f / 1.8f, S9c, C0))) * inv_n;
        }
    }

    if (lane == 0) lds_cap[wave] = loss;
    __syncthreads();
    if (threadIdx.x == 0) {
        atomicAdd(out, lds_cap[0] + lds_cap[1] + lds_cap[2] + lds_cap[3]);
    }
}

extern "C" void kernel_launch(void* const* d_in, const int* in_sizes, int n_in,
                              void* d_out, int out_size, void* d_ws, size_t ws_size,
                              hipStream_t stream) {
    const float* inputs  = (const float*)d_in[0];
    const float* targets = (const float*)d_in[1];
    float* out = (float*)d_out;

    const int N = in_sizes[0] / C_DIM;

    // Smoothed one-hot targets take 2 values; per-elem loss = F - E*r4 + r9/1.8.
    // Row sum = C0 - E_off*S4 - (E_on-E_off)*r4_hot + S9/1.8, C0 = 999*F_off + F_on.
    const double ls    = 0.05;
    const double c1g_d = 1.0 - (1000.0 / 999.0) * ls;
    const double c2_d  = ls / 999.0;
    const float  tp_on_f  = (float)c1g_d + (float)c2_d;
    const float  tp_off_f = (float)c2_d;
    const double tp_on  = (double)tp_on_f;
    const double tp_off = (double)tp_off_f;
    const double A_on  = (pow(tp_on  + 1e-8, 0.8) - 1.0) / 0.8;
    const double A_off = (pow(tp_off + 1e-8, 0.8) - 1.0) / 0.8;
    const double B_on  = pow(tp_on,  1.8);
    const double B_off = pow(tp_off, 1.8);
    const double E_on_d  = 1.25 * tp_on;
    const double E_off_d = 1.25 * tp_off;
    const double F_on_d  = tp_on  * A_on  + E_on_d  - B_on  / 1.8;
    const double F_off_d = tp_off * A_off + E_off_d - B_off / 1.8;
    const double C0_d    = (C_DIM - 1) * F_off_d + F_on_d;
    const double dE_d    = E_on_d - E_off_d;

    hipMemsetAsync(out, 0, sizeof(float), stream);   // graph-capturable
    dim3 grid((N + 3) / 4);
    btll<<<grid, 256, 0, stream>>>(inputs, targets, out, N, 1.0f / (float)N,
                                   (float)C0_d, (float)E_off_d, (float)dE_d);
}

// Round 7
// 146.953 us; speedup vs baseline: 1.1246x; 1.1246x over previous
//
#include <hip/hip_runtime.h>
#include <math.h>

#define C_DIM 1000
#define BIG   1.0e30f   // pad: u huge -> rcp underflows -> 0 in every sum (self-masking)

__device__ __forceinline__ float fexp2(float x) { return __builtin_amdgcn_exp2f(x); }
__device__ __forceinline__ float flog2(float x) { return __builtin_amdgcn_logf(x); }
__device__ __forceinline__ float frcp(float x)  { return __builtin_amdgcn_rcpf(x); }

// ---- DPP wave64 reductions (VALU pipe; ~10x lower latency than shfl/bpermute) ----
// sum: moved-in value 0 for invalid/masked lanes (bound_ctrl=1, old=0) -> add identity
template <int CTRL, int RM>
__device__ __forceinline__ float dpp_add_term(float x) {
    int y = __builtin_amdgcn_update_dpp(0, __float_as_int(x), CTRL, RM, 0xf, true);
    return __int_as_float(y);
}
// max: invalid/masked lanes keep old=x -> fmax identity
template <int CTRL, int RM>
__device__ __forceinline__ float dpp_max_term(float x) {
    int y = __builtin_amdgcn_update_dpp(__float_as_int(x), __float_as_int(x), CTRL, RM, 0xf, false);
    return __int_as_float(y);
}

#define DPP_SUM_CHAIN(x)                      \
    x += dpp_add_term<0x111, 0xf>(x);         \
    x += dpp_add_term<0x112, 0xf>(x);         \
    x += dpp_add_term<0x114, 0xf>(x);         \
    x += dpp_add_term<0x118, 0xf>(x);         \
    x += dpp_add_term<0x142, 0xa>(x);         \
    x += dpp_add_term<0x143, 0xc>(x);

__device__ __forceinline__ float bcast63(float x) {
    return __int_as_float(__builtin_amdgcn_readlane(__float_as_int(x), 63));
}

__device__ __forceinline__ float wave_sum(float x) {
    DPP_SUM_CHAIN(x)
    return bcast63(x);
}

__device__ __forceinline__ float wave_max(float x) {
    x = fmaxf(x, dpp_max_term<0x111, 0xf>(x));
    x = fmaxf(x, dpp_max_term<0x112, 0xf>(x));
    x = fmaxf(x, dpp_max_term<0x114, 0xf>(x));
    x = fmaxf(x, dpp_max_term<0x118, 0xf>(x));
    x = fmaxf(x, dpp_max_term<0x142, 0xa>(x));
    x = fmaxf(x, dpp_max_term<0x143, 0xc>(x));
    return bcast63(x);
}

// One wave per row; grid 4096 x 4 waves = 2 full-occupancy generations
// (gen-2 loads stream under gen-1 compute -- R3's proven overlap mechanism).
__global__ __launch_bounds__(256) void btll(
    const float* __restrict__ inputs, const float* __restrict__ targets,
    float* __restrict__ row_out, int n_rows,
    float C0, float E_off, float dE)
{
    const int lane = threadIdx.x & 63;
    const int wave = threadIdx.x >> 6;
    const int row  = blockIdx.x * 4 + wave;
    if (row >= n_rows) return;

    const float4* in4 = (const float4*)(inputs  + (size_t)row * C_DIM);
    const float4* tg4 = (const float4*)(targets + (size_t)row * C_DIM);
    const bool m3 = (lane + 192) < 250;   // only the 4th chunk needs tail masking

    // ---- issue all 8 coalesced 16B loads up front ----
    float4 x0 = in4[lane];
    float4 x1 = in4[lane + 64];
    float4 x2 = in4[lane + 128];
    float4 x3 = m3 ? in4[lane + 192] : make_float4(-BIG, -BIG, -BIG, -BIG);
    float4 t0 = tg4[lane];
    float4 t1 = tg4[lane + 64];
    float4 t2 = tg4[lane + 128];
    float4 t3 = m3 ? tg4[lane + 192] : make_float4(0.f, 0.f, 0.f, 0.f);

    float a[16];
    a[0]=x0.x; a[1]=x0.y; a[2]=x0.z; a[3]=x0.w;
    a[4]=x1.x; a[5]=x1.y; a[6]=x1.z; a[7]=x1.w;
    a[8]=x2.x; a[9]=x2.y; a[10]=x2.z; a[11]=x2.w;
    a[12]=x3.x; a[13]=x3.y; a[14]=x3.z; a[15]=x3.w;

    // hot-class logit (targets are raw one-hot {0,1}) + row max
    float ah = 0.0f;
    ah = fmaf(t0.x, a[0], ah);  ah = fmaf(t0.y, a[1], ah);
    ah = fmaf(t0.z, a[2], ah);  ah = fmaf(t0.w, a[3], ah);
    ah = fmaf(t1.x, a[4], ah);  ah = fmaf(t1.y, a[5], ah);
    ah = fmaf(t1.z, a[6], ah);  ah = fmaf(t1.w, a[7], ah);
    ah = fmaf(t2.x, a[8], ah);  ah = fmaf(t2.y, a[9], ah);
    ah = fmaf(t2.z, a[10], ah); ah = fmaf(t2.w, a[11], ah);
    ah = fmaf(t3.x, a[12], ah); ah = fmaf(t3.y, a[13], ah);
    ah = fmaf(t3.z, a[14], ah); ah = fmaf(t3.w, a[15], ah);

    float mu = a[0];
    #pragma unroll
    for (int k = 1; k < 16; ++k) mu = fmaxf(mu, a[k]);
    mu = wave_max(mu);
    ah = wave_sum(ah);

    float b[16];
    #pragma unroll
    for (int k = 0; k < 16; ++k) b[k] = -0.2f * (a[k] - mu);  // >= 0; pad -> ~2e29
    const float hb = -0.2f * (ah - mu);

    // ---- sweep 1: FP at lam=1 ----
    float s = 0.0f;
    #pragma unroll
    for (int k = 0; k < 16; ++k) {
        float u = 1.0f + b[k];
        float u2 = u * u;
        s += frcp(u2 * u2 * u);
    }
    s = wave_sum(s);
    const float lam = fexp2(-0.2f * flog2(s));

    // ---- sweep 2: FP at lam -> w0 = s^0.2 (below root; Newton-safe) ----
    s = 0.0f;
    #pragma unroll
    for (int k = 0; k < 16; ++k) {
        float u = fmaf(lam, b[k], 1.0f);
        float u2 = u * u;
        s += frcp(u2 * u2 * u);
    }
    s = wave_sum(s);
    const float w = fexp2(0.2f * flog2(s));

    // ---- sweep 3: merged Newton + loss sums, 2nd-order corrected to w+delta ----
    float S4 = 0.0f, S5 = 0.0f, S6 = 0.0f, S9 = 0.0f, S10 = 0.0f, S11 = 0.0f;
    #pragma unroll
    for (int k = 0; k < 16; ++k) {
        float r  = frcp(w + b[k]);
        float r2 = r * r;
        float r4 = r2 * r2;
        float r5 = r4 * r;
        float r9 = r4 * r5;
        S4  += r4;
        S5  += r5;
        S6  += r5 * r;
        S9  += r9;
        S10 += r5 * r5;
        S11 += r9 * r2;
    }
    DPP_SUM_CHAIN(S4)
    DPP_SUM_CHAIN(S5)
    DPP_SUM_CHAIN(S6)
    DPP_SUM_CHAIN(S9)
    DPP_SUM_CHAIN(S10)
    DPP_SUM_CHAIN(S11)
    S4 = bcast63(S4);  S5 = bcast63(S5);  S6 = bcast63(S6);
    S9 = bcast63(S9);  S10 = bcast63(S10); S11 = bcast63(S11);

    const float d   = (S5 - 1.0f) * 0.2f * frcp(S6);            // Newton step (~5e-3)
    const float w1  = w + d;
    const float d2  = d * d;
    const float S4c = S4 + fmaf(10.0f * d2, S6,  -4.0f * d * S5);   // S4(w1) + O(d^3)
    const float S9c = S9 + fmaf(45.0f * d2, S11, -9.0f * d * S10);  // S9(w1) + O(d^3)
    const float rh  = frcp(w1 + hb);
    const float rh2 = rh * rh;
    const float rh4 = rh2 * rh2;

    const float loss = fmaf(-E_off, S4c,
                       fmaf(-dE, rh4,
                       fmaf(1.0f / 1.8f, S9c, C0)));
    if (lane == 0) row_out[row] = loss;
}

__global__ __launch_bounds__(1024) void reduce_mean(
    const float* __restrict__ row_out, float* __restrict__ out, int n)
{
    __shared__ double sm[16];
    const int lane = threadIdx.x & 63;
    const int wv   = threadIdx.x >> 6;
    double s = 0.0;
    for (int i = threadIdx.x; i < n; i += 1024) s += (double)row_out[i];
    #pragma unroll
    for (int off = 32; off > 0; off >>= 1) s += __shfl_xor(s, off, 64);
    if (lane == 0) sm[wv] = s;
    __syncthreads();
    if (wv == 0) {
        double t = (lane < 16) ? sm[lane] : 0.0;
        #pragma unroll
        for (int off = 32; off > 0; off >>= 1) t += __shfl_xor(t, off, 64);
        if (lane == 0) out[0] = (float)(t / (double)n);
    }
}

extern "C" void kernel_launch(void* const* d_in, const int* in_sizes, int n_in,
                              void* d_out, int out_size, void* d_ws, size_t ws_size,
                              hipStream_t stream) {
    const float* inputs  = (const float*)d_in[0];
    const float* targets = (const float*)d_in[1];
    float* out = (float*)d_out;

    const int N = in_sizes[0] / C_DIM;
    float* row_out = (float*)d_ws;

    // Smoothed one-hot targets take 2 values; per-elem loss = F - E*r4 + r9/1.8.
    // Row sum = C0 - E_off*S4 - (E_on-E_off)*r4_hot + S9/1.8, C0 = 999*F_off + F_on.
    const double ls    = 0.05;
    const double c1g_d = 1.0 - (1000.0 / 999.0) * ls;
    const double c2_d  = ls / 999.0;
    const float  tp_on_f  = (float)c1g_d + (float)c2_d;
    const float  tp_off_f = (float)c2_d;
    const double tp_on  = (double)tp_on_f;
    const double tp_off = (double)tp_off_f;
    const double A_on  = (pow(tp_on  + 1e-8, 0.8) - 1.0) / 0.8;
    const double A_off = (pow(tp_off + 1e-8, 0.8) - 1.0) / 0.8;
    const double B_on  = pow(tp_on,  1.8);
    const double B_off = pow(tp_off, 1.8);
    const double E_on_d  = 1.25 * tp_on;
    const double E_off_d = 1.25 * tp_off;
    const double F_on_d  = tp_on  * A_on  + E_on_d  - B_on  / 1.8;
    const double F_off_d = tp_off * A_off + E_off_d - B_off / 1.8;
    const double C0_d    = (C_DIM - 1) * F_off_d + F_on_d;
    const double dE_d    = E_on_d - E_off_d;

    dim3 grid((N + 3) / 4);
    btll<<<grid, 256, 0, stream>>>(inputs, targets, row_out, N,
                                   (float)C0_d, (float)E_off_d, (float)dE_d);
    reduce_mean<<<1, 1024, 0, stream>>>(row_out, out, N);
}